// Round 3
// baseline (390.828 us; speedup 1.0000x reference)
//
#include <hip/hip_runtime.h>
#include <cstdint>

#define M_DIM 65536
#define N_DIM 512
#define K_DIM 512
#define BM 128
#define BN 128
#define BK 32
#define KSTEPS (K_DIM / BK)

typedef float f32x4 __attribute__((ext_vector_type(4)));
typedef __bf16 bf16x8 __attribute__((ext_vector_type(8)));
typedef unsigned short us8 __attribute__((ext_vector_type(8)));

__device__ __forceinline__ unsigned short f2bf(float f) {
  unsigned int u = __builtin_bit_cast(unsigned int, f);
  u += 0x7fffu + ((u >> 16) & 1u);  // round-to-nearest-even
  return (unsigned short)(u >> 16);
}

// ---------------------------------------------------------------------------
// Prep: WCT[(o*8+k)*512 + n*8+i] = bf16( sum_j nan0(weight[o,n,j]*rs[o]*cs[n]) * C[i,j,k] )
//       bias2[o*8+k] = bias[o,k] + (k==0)*bias_shift[o]
// ---------------------------------------------------------------------------
__global__ void clifford_prep(const float* __restrict__ weight,
                              const float* __restrict__ bias,
                              const float* __restrict__ row_scale,
                              const float* __restrict__ col_scale,
                              const float* __restrict__ bias_shift,
                              unsigned short* __restrict__ WCT,
                              float* __restrict__ bias2) {
  const int t = blockIdx.x * 256 + threadIdx.x;
  if (t < 512) {
    const int o = t >> 3, k = t & 7;
    bias2[t] = bias[t] + (k == 0 ? bias_shift[o] : 0.0f);
  }
  if (t >= 64 * 64) return;
  const int o = t >> 6, n = t & 63;
  const float rs = row_scale[o], cs = col_scale[n];
  float w[8];
#pragma unroll
  for (int j = 0; j < 8; ++j) {
    float v = weight[(size_t)t * 8 + j] * rs * cs;
    w[j] = (v != v) ? 0.0f : v;  // nan_to_num
  }
  constexpr int TI[64] = {0,1,2,3,4,5,6,7, 0,1,2,4,3,5,6,7, 0,2,1,4,3,6,5,7,
                          0,3,1,5,2,6,4,7, 0,4,1,2,3,7,5,6, 0,5,1,3,2,7,4,6,
                          0,6,2,3,1,7,4,5, 0,7,1,6,2,5,3,4};
  constexpr int TJ[64] = {0,1,2,3,4,5,6,7, 1,0,4,2,5,3,7,6, 2,0,4,1,6,3,7,5,
                          3,0,5,1,6,2,7,4, 4,0,2,1,7,3,6,5, 5,0,3,1,7,2,6,4,
                          6,0,3,2,7,1,5,4, 7,0,6,1,5,2,4,3};
  constexpr int TK[64] = {0,0,0,0,0,0,0,0, 1,1,1,1,1,1,1,1, 2,2,2,2,2,2,2,2,
                          3,3,3,3,3,3,3,3, 4,4,4,4,4,4,4,4, 5,5,5,5,5,5,5,5,
                          6,6,6,6,6,6,6,6, 7,7,7,7,7,7,7,7};
  constexpr float TS[64] = {1,1,1,1,-1,-1,-1,-1, 1,1,-1,1,-1,1,-1,-1, 1,1,1,-1,-1,1,1,1,
                            1,1,1,-1,1,-1,-1,-1, 1,1,1,-1,1,1,-1,1,  1,1,1,-1,-1,-1,1,-1,
                            1,1,1,-1,1,1,-1,1,   1,1,1,1,-1,-1,1,1};
  float wc[8][8];
#pragma unroll
  for (int i = 0; i < 8; ++i)
#pragma unroll
    for (int k = 0; k < 8; ++k) wc[i][k] = 0.0f;
#pragma unroll
  for (int e = 0; e < 64; ++e) wc[TI[e]][TK[e]] += TS[e] * w[TJ[e]];
#pragma unroll
  for (int k = 0; k < 8; ++k)
#pragma unroll
    for (int i = 0; i < 8; ++i)
      WCT[(size_t)(o * 8 + k) * K_DIM + (n * 8 + i)] = f2bf(wc[i][k]);
}

// ---------------------------------------------------------------------------
// GEMM: out[M,N] = x[M,K] * WCT^T  (+ bias2 epilogue)
// No LDS, no barriers: each wave loads its MFMA fragments directly from
// global (A: fp32 -> v_cvt_pk_bf16_f32; B: bf16, L2-resident) with a 1-step
// register prefetch. Fine-grained vmcnt waits replace the barrier drain;
// waves pipeline independently. XCD swizzle keeps the 4 n-tiles of an
// m-tile on one XCD (x fetched from HBM once, re-reads from L1/L2/LLC).
// ---------------------------------------------------------------------------
__global__ __launch_bounds__(256) void clifford_gemm(
    const float* __restrict__ x, const unsigned short* __restrict__ WCT,
    const float* __restrict__ bias2, float* __restrict__ out) {
  const int tid = threadIdx.x;
  const int lane = tid & 63;
  const int wv = tid >> 6;

  // XCD swizzle: grid = 2048 = 64 groups x 32; r&7 = XCD (round-robin),
  // r>>3 = n-tile -> 4 n-tiles of one m-tile land on the same XCD.
  const int bid = blockIdx.x;
  const int grp = bid >> 5, r = bid & 31;
  const size_t m0 = (size_t)(grp * 8 + (r & 7)) * BM;
  const int n0 = (r >> 3) * BN;

  // fragment geometry (16x16x32: operand element k = (lane>>4)*8 + j)
  const int wm = (wv & 1) * 64;
  const int wn = (wv >> 1) * 64;
  const int lm = lane & 15;
  const int kg = lane >> 4;  // 0..3

  const float* aBase = x + (m0 + wm + lm) * (size_t)K_DIM + kg * 8;
  const unsigned short* bBase = WCT + (size_t)(n0 + wn + lm) * K_DIM + kg * 8;

  const f32x4 zero = {0.f, 0.f, 0.f, 0.f};
  f32x4 acc[4][4];
#pragma unroll
  for (int i = 0; i < 4; ++i)
#pragma unroll
    for (int j = 0; j < 4; ++j) acc[i][j] = zero;

  // double-buffered raw fragment registers (1-step prefetch)
  f32x4 alo[2][4], ahi[2][4];
  us8 braw[2][4];

#define LOAD_STEP(BUF, KS)                                                   \
  {                                                                          \
    _Pragma("unroll") for (int mi = 0; mi < 4; ++mi) {                       \
      const float* p = aBase + (size_t)mi * 16 * K_DIM + (KS) * BK;          \
      alo[BUF][mi] = *(const f32x4*)p;                                       \
      ahi[BUF][mi] = *(const f32x4*)(p + 4);                                 \
    }                                                                        \
    _Pragma("unroll") for (int ni = 0; ni < 4; ++ni) {                       \
      braw[BUF][ni] =                                                        \
          *(const us8*)(bBase + (size_t)ni * 16 * K_DIM + (KS) * BK);        \
    }                                                                        \
  }

#define COMPUTE_STEP(BUF)                                                    \
  {                                                                          \
    bf16x8 af[4];                                                            \
    _Pragma("unroll") for (int mi = 0; mi < 4; ++mi) {                       \
      union { bf16x8 v; __bf16 e[8]; } cv;                                   \
      _Pragma("unroll") for (int j = 0; j < 4; ++j) {                        \
        cv.e[j] = (__bf16)alo[BUF][mi][j];                                   \
        cv.e[4 + j] = (__bf16)ahi[BUF][mi][j];                               \
      }                                                                      \
      af[mi] = cv.v;                                                         \
    }                                                                        \
    _Pragma("unroll") for (int mi = 0; mi < 4; ++mi)                         \
        _Pragma("unroll") for (int ni = 0; ni < 4; ++ni) {                   \
      acc[mi][ni] = __builtin_amdgcn_mfma_f32_16x16x32_bf16(                 \
          af[mi], __builtin_bit_cast(bf16x8, braw[BUF][ni]), acc[mi][ni],    \
          0, 0, 0);                                                          \
    }                                                                        \
  }

  LOAD_STEP(0, 0)
#pragma unroll
  for (int kp = 0; kp < KSTEPS / 2; ++kp) {
    LOAD_STEP(1, 2 * kp + 1)
    COMPUTE_STEP(0)
    if (kp < KSTEPS / 2 - 1) LOAD_STEP(0, 2 * kp + 2)
    COMPUTE_STEP(1)
  }
#undef LOAD_STEP
#undef COMPUTE_STEP

  // epilogue: C/D layout col=lane&15 (n), row=(lane>>4)*4+reg (m)
#pragma unroll
  for (int ni = 0; ni < 4; ++ni) {
    const int nn = n0 + wn + ni * 16 + lm;
    const float b2 = bias2[nn];
#pragma unroll
    for (int mi = 0; mi < 4; ++mi) {
#pragma unroll
      for (int rr = 0; rr < 4; ++rr) {
        const size_t mm = m0 + wm + mi * 16 + kg * 4 + rr;
        out[mm * N_DIM + nn] = acc[mi][ni][rr] + b2;
      }
    }
  }
}

extern "C" void kernel_launch(void* const* d_in, const int* in_sizes, int n_in,
                              void* d_out, int out_size, void* d_ws, size_t ws_size,
                              hipStream_t stream) {
  const float* x          = (const float*)d_in[0];
  const float* weight     = (const float*)d_in[1];
  const float* bias       = (const float*)d_in[2];
  const float* row_scale  = (const float*)d_in[3];
  const float* col_scale  = (const float*)d_in[4];
  const float* bias_shift = (const float*)d_in[5];

  unsigned short* WCT = (unsigned short*)d_ws;                       // 512*512*2 B
  float* bias2 = (float*)((char*)d_ws + (size_t)N_DIM * K_DIM * 2);  // +2 KB

  clifford_prep<<<16, 256, 0, stream>>>(weight, bias, row_scale, col_scale,
                                        bias_shift, WCT, bias2);
  clifford_gemm<<<(M_DIM / BM) * (N_DIM / BN), 256, 0, stream>>>(
      x, WCT, bias2, (float*)d_out);
}